// Round 10
// baseline (687.645 us; speedup 1.0000x reference)
//
#include <hip/hip_runtime.h>
#include <hip/hip_bf16.h>
#include <math.h>

#define C_DIM 256
#define HWDIM 256
#define CH_STRIDE (HWDIM * HWDIM)      // 65536 floats between channels
#define R_DIM 32

typedef float nfloat4 __attribute__((ext_vector_type(4)));  // for nt-store

// Persistent-block pipelined version. grid = 256 blocks (1 per CU), 1024 thr.
// Block bid owns one 8-row band of image bimg = bid>>5 (rows H0c..H0c+7,
// H0c = (bid&31)*8) and sweeps 8 groups of 4 patches left->right (g*32 cols).
// Per group: 8 rows x 32 cols x 256 ch, exclusive 128B lines (R3 invariant).
// Pipeline: prefetch group g+1's 16 float4 (nv, 64 VGPR) at the top of group
// g's compute, consume after g's stores -> HBM busy during reduce/MLP phases.
// Persistent x-cache in bf16 (vlo/vhi, 32 VGPR). launch_bounds(1024,2) -> VGPR
// cap 128 (cap = 256/arg, est. need ~115): no spills, full load ILP.
__global__ __launch_bounds__(1024, 2)
void lpa_fused_kernel(const float* __restrict__ x,
                      const float* __restrict__ gamma,
                      const float* __restrict__ beta,
                      const float* __restrict__ w1,
                      const float* __restrict__ w2,
                      float* __restrict__ out)
{
    __shared__ float sp[16 * 256];     // per-wave partial sums  [wid][pixel]
    __shared__ float sq[16 * 256];     // per-wave partial sumsq [wid][pixel]
    __shared__ float mu_s[256];
    __shared__ float rs_s[256];
    __shared__ float gs[C_DIM];
    __shared__ float bs[C_DIM];
    __shared__ float pm_s[4 * C_DIM];  // [patch][c]
    __shared__ float h_s[4 * R_DIM];   // [patch][r]
    __shared__ float2 AB_s[4 * C_DIM]; // [patch][c] = (gamma*gate, beta*gate)

    const int t    = threadIdx.x;
    const int wid  = t >> 6;
    const int lane = t & 63;
    const int hh   = lane >> 3;        // row in band 0..7
    const int wq   = lane & 7;         // float4 col 0..7 within group
    const int pat  = wq >> 1;          // patch 0..3 within the group
    const int p0   = hh * 32 + wq * 4; // first pixel (0..255)

    const int bid  = blockIdx.x;
    const int bimg = bid >> 5;         // image 0..7
    const int H0c  = (bid & 31) * 8;   // band row origin
    const unsigned ubase = (unsigned)bimg * (C_DIM * CH_STRIDE)
                         + (unsigned)(H0c + hh) * HWDIM
                         + (unsigned)wq * 4u
                         + (unsigned)wid * 16u * CH_STRIDE;
    const float* xb0 = x + ubase;      // group g adds g*32; channel k adds k*CH
    float* ob0 = out + ubase;

    if (t < C_DIM) { gs[t] = gamma[t]; bs[t] = beta[t]; }

    // ---- prologue: load group 0, stats + bf16-convert ----
    float4 nv[16];
#pragma unroll
    for (int k = 0; k < 16; ++k)
        nv[k] = *reinterpret_cast<const float4*>(xb0 + (unsigned)k * CH_STRIDE);
    __hip_bfloat162 vlo[16], vhi[16];
    {
        float s0 = 0.f, s1 = 0.f, s2 = 0.f, s3 = 0.f;
        float q0 = 0.f, q1 = 0.f, q2 = 0.f, q3 = 0.f;
#pragma unroll
        for (int k = 0; k < 16; ++k) {
            float4 f = nv[k];
            s0 += f.x; q0 += f.x * f.x;
            s1 += f.y; q1 += f.y * f.y;
            s2 += f.z; q2 += f.z * f.z;
            s3 += f.w; q3 += f.w * f.w;
            vlo[k] = __float22bfloat162_rn(make_float2(f.x, f.y));
            vhi[k] = __float22bfloat162_rn(make_float2(f.z, f.w));
        }
        *reinterpret_cast<float4*>(&sp[wid * 256 + p0]) = make_float4(s0, s1, s2, s3);
        *reinterpret_cast<float4*>(&sq[wid * 256 + p0]) = make_float4(q0, q1, q2, q3);
    }
    __syncthreads();

    for (int g = 0; g < 8; ++g) {
        // ---- stage 2: finalize per-pixel LN stats for group g ----
        if (t < 256) {
            float s = 0.f, q = 0.f;
#pragma unroll
            for (int w = 0; w < 16; ++w) {
                s += sp[w * 256 + t];
                q += sq[w * 256 + t];
            }
            float mu  = s * (1.0f / 256.0f);
            float var = q * (1.0f / 256.0f) - mu * mu;
            mu_s[t] = mu;
            rs_s[t] = rsqrtf(var + 1e-5f);
        }
        // ---- prefetch group g+1 (flies across stages 3-5) ----
        if (g < 7) {
            const float* xn = xb0 + (unsigned)(g + 1) * 32u;
#pragma unroll
            for (int k = 0; k < 16; ++k)
                nv[k] = *reinterpret_cast<const float4*>(xn + (unsigned)k * CH_STRIDE);
        }
        __syncthreads();

        const float4 mu4 = *reinterpret_cast<const float4*>(&mu_s[p0]);
        const float4 rs4 = *reinterpret_cast<const float4*>(&rs_s[p0]);

        // ---- stage 3: per-(patch, channel) mean of normalized values ----
#pragma unroll
        for (int k = 0; k < 16; ++k) {
            int c = wid * 16 + k;
            float2 xy = __bfloat1622float2(vlo[k]);
            float2 zw = __bfloat1622float2(vhi[k]);
            float ws = rs4.x * (xy.x - mu4.x) + rs4.y * (xy.y - mu4.y)
                     + rs4.z * (zw.x - mu4.z) + rs4.w * (zw.y - mu4.w);
            ws += __shfl_xor(ws, 1);
            ws += __shfl_xor(ws, 8);
            ws += __shfl_xor(ws, 16);
            ws += __shfl_xor(ws, 32);
            if ((lane & 57) == 0)      // lanes 0,2,4,6 -> patches 0..3
                pm_s[pat * C_DIM + c] = gs[c] * ws * (1.0f / 64.0f) + bs[c];
        }
        __syncthreads();

        // ---- stage 4a: h = silu(w1 @ pm); w1 [32][256] row-major ----
        {
            const int pat4 = t >> 8;
            const int r    = (t >> 3) & 31;
            const int k8   = t & 7;
            const float4* wrow = reinterpret_cast<const float4*>(w1 + r * C_DIM + k8 * 32);
            const float* pmk = &pm_s[pat4 * C_DIM + k8 * 32];
            float s = 0.f;
#pragma unroll
            for (int j = 0; j < 8; ++j) {
                float4 wv = wrow[j];
                float4 pv = *reinterpret_cast<const float4*>(pmk + j * 4);
                s += wv.x * pv.x + wv.y * pv.y + wv.z * pv.z + wv.w * pv.w;
            }
            s += __shfl_down(s, 4, 8);
            s += __shfl_down(s, 2, 8);
            s += __shfl_down(s, 1, 8);
            if (k8 == 0) {
                float sig = 1.0f / (1.0f + __expf(-s));
                h_s[pat4 * R_DIM + r] = s * sig;
            }
        }
        __syncthreads();

        // ---- stage 4b: gate = sigmoid(w2 @ h); fold gamma/beta ----
        {
            const int pat4 = t >> 8;
            const int c4   = t & 255;
            const float4* wrow = reinterpret_cast<const float4*>(w2 + c4 * R_DIM);
            const float* hk = &h_s[pat4 * R_DIM];
            float s = 0.f;
#pragma unroll
            for (int j = 0; j < 8; ++j) {
                float4 wv = wrow[j];
                s += wv.x * hk[j * 4 + 0] + wv.y * hk[j * 4 + 1]
                   + wv.z * hk[j * 4 + 2] + wv.w * hk[j * 4 + 3];
            }
            float gate = 1.0f / (1.0f + __expf(-s));
            AB_s[pat4 * C_DIM + c4] = make_float2(gs[c4] * gate, bs[c4] * gate);
        }
        __syncthreads();

        // ---- stage 5: gated nt-stores from bf16 regs ----
        {
            float* ob = ob0 + (unsigned)g * 32u;
#pragma unroll
            for (int k = 0; k < 16; ++k) {
                int c = wid * 16 + k;
                float2 ab = AB_s[pat * C_DIM + c];
                float2 xy = __bfloat1622float2(vlo[k]);
                float2 zw = __bfloat1622float2(vhi[k]);
                nfloat4 o;
                o.x = ab.x * rs4.x * (xy.x - mu4.x) + ab.y;
                o.y = ab.x * rs4.y * (xy.y - mu4.y) + ab.y;
                o.z = ab.x * rs4.z * (zw.x - mu4.z) + ab.y;
                o.w = ab.x * rs4.w * (zw.y - mu4.w) + ab.y;
                __builtin_nontemporal_store(o,
                    reinterpret_cast<nfloat4*>(ob + (unsigned)k * CH_STRIDE));
            }
        }
        // ---- consume prefetch: stats + bf16-convert for group g+1 ----
        if (g < 7) {
            float s0 = 0.f, s1 = 0.f, s2 = 0.f, s3 = 0.f;
            float q0 = 0.f, q1 = 0.f, q2 = 0.f, q3 = 0.f;
#pragma unroll
            for (int k = 0; k < 16; ++k) {
                float4 f = nv[k];
                s0 += f.x; q0 += f.x * f.x;
                s1 += f.y; q1 += f.y * f.y;
                s2 += f.z; q2 += f.z * f.z;
                s3 += f.w; q3 += f.w * f.w;
                vlo[k] = __float22bfloat162_rn(make_float2(f.x, f.y));
                vhi[k] = __float22bfloat162_rn(make_float2(f.z, f.w));
            }
            *reinterpret_cast<float4*>(&sp[wid * 256 + p0]) = make_float4(s0, s1, s2, s3);
            *reinterpret_cast<float4*>(&sq[wid * 256 + p0]) = make_float4(q0, q1, q2, q3);
        }
        __syncthreads();
    }
}

extern "C" void kernel_launch(void* const* d_in, const int* in_sizes, int n_in,
                              void* d_out, int out_size, void* d_ws, size_t ws_size,
                              hipStream_t stream) {
    const float* x     = (const float*)d_in[0];
    const float* gamma = (const float*)d_in[1];
    const float* beta  = (const float*)d_in[2];
    const float* w1    = (const float*)d_in[3];
    const float* w2    = (const float*)d_in[4];
    float* out = (float*)d_out;

    // 256 persistent blocks (1/CU), each sweeps 8 groups of a row-band.
    lpa_fused_kernel<<<256, 1024, 0, stream>>>(x, gamma, beta, w1, w2, out);
}

// Round 11
// 246.878 us; speedup vs baseline: 2.7854x; 2.7854x over previous
//
#include <hip/hip_runtime.h>
#include <math.h>

#define C_DIM 256
#define HWDIM 256
#define CH_STRIDE (HWDIM * HWDIM)      // 65536 floats between channels
#define R_DIM 32
#define PS_PITCH 65                    // ps[c][64 slots], padded pitch

typedef float nfloat4 __attribute__((ext_vector_type(4)));  // for nt-store

// Block = 4 horizontally-adjacent 8x8 patches: region 8 rows x 32 cols x 256 ch.
// 1024 threads = 16 waves. Wave `wid` owns channels c = wid*16 + k, k=0..15.
// Lane l: row hh = l>>3, float4-col wq = l&7 -> one wave-instr = one channel's
// full 8x32 tile = 8 dense 128B lines; NO 128B line is shared between blocks.
// v[16] f32 register cache (64 VGPR).
// NO __launch_bounds__: every launch_bounds variant observed (R2/R5/R7/R10)
// silently capped VGPR to 64 or 32 and spilled the register cache to scratch
// (R10: +900MB write traffic). With wg=1024 the hardware alone enforces a
// 128-VGPR ceiling (4 waves/SIMD must fit), and the ~100 needed fits freely.
__global__
void lpa_fused_kernel(const float* __restrict__ x,
                      const float* __restrict__ gamma,
                      const float* __restrict__ beta,
                      const float* __restrict__ w1,
                      const float* __restrict__ w2,
                      float* __restrict__ out)
{
    __shared__ float sp[16 * 256];     // per-wave partial sums  [wid][pixel]
    __shared__ float sq[16 * 256];     // per-wave partial sumsq [wid][pixel]
    __shared__ float ps[C_DIM * PS_PITCH]; // [c][slot] pm partials, padded
    __shared__ float mu_s[256];
    __shared__ float rs_s[256];
    __shared__ float gs[C_DIM];
    __shared__ float bs[C_DIM];
    __shared__ float pm_s[4 * C_DIM];  // [patch][c]
    __shared__ float h_s[4 * R_DIM];   // [patch][r]
    __shared__ float2 AB_s[4 * C_DIM]; // [patch][c] = (gamma*gate, beta*gate)

    const int t    = threadIdx.x;
    const int wid  = t >> 6;
    const int lane = t & 63;
    const int hh   = lane >> 3;        // row in region 0..7
    const int wq   = lane & 7;         // float4 col 0..7
    const int pat  = wq >> 1;          // patch 0..3 within the group
    const int p0   = hh * 32 + wq * 4; // first pixel (0..255)
    // slot within the 64 per-channel partials; bijective over the 64 lanes,
    // grouped so slots [pat*16, pat*16+16) are exactly patch `pat`.
    const int slot = pat * 16 + hh * 2 + (wq & 1);

    const int bid = blockIdx.x;
    const int b   = bid >> 8;          // 256 groups per image (32 gh x 8 gw)
    const int ij  = bid & 255;
    const unsigned H0 = (unsigned)(ij >> 3) * 8u;
    const unsigned W0 = (unsigned)(ij & 7) * 32u;
    const unsigned baseb  = (unsigned)b * (C_DIM * CH_STRIDE);
    const unsigned rowoff = baseb + (H0 + hh) * HWDIM + W0 + (unsigned)wq * 4u;

    if (t < C_DIM) { gs[t] = gamma[t]; bs[t] = beta[t]; }

    const float* xb = x + rowoff + (unsigned)wid * 16u * CH_STRIDE;

    // ---- Stage 1: load 16 channel-tiles into regs + per-pixel partial stats ----
    float4 v[16];
    float s0 = 0.f, s1 = 0.f, s2 = 0.f, s3 = 0.f;
    float q0 = 0.f, q1 = 0.f, q2 = 0.f, q3 = 0.f;
#pragma unroll
    for (int k = 0; k < 16; ++k) {
        v[k] = *reinterpret_cast<const float4*>(xb + (unsigned)k * CH_STRIDE);
        s0 += v[k].x; q0 += v[k].x * v[k].x;
        s1 += v[k].y; q1 += v[k].y * v[k].y;
        s2 += v[k].z; q2 += v[k].z * v[k].z;
        s3 += v[k].w; q3 += v[k].w * v[k].w;
    }
    *reinterpret_cast<float4*>(&sp[wid * 256 + p0]) = make_float4(s0, s1, s2, s3);
    *reinterpret_cast<float4*>(&sq[wid * 256 + p0]) = make_float4(q0, q1, q2, q3);
    __syncthreads();

    // ---- Stage 2: finalize per-pixel LN stats (256 threads, one per pixel) ----
    if (t < 256) {
        float s = 0.f, q = 0.f;
#pragma unroll
        for (int w = 0; w < 16; ++w) {
            s += sp[w * 256 + t];
            q += sq[w * 256 + t];
        }
        float mu  = s * (1.0f / 256.0f);
        float var = q * (1.0f / 256.0f) - mu * mu;
        mu_s[t] = mu;
        rs_s[t] = rsqrtf(var + 1e-5f);
    }
    __syncthreads();

    const float4 mu4 = *reinterpret_cast<const float4*>(&mu_s[p0]);
    const float4 rs4 = *reinterpret_cast<const float4*>(&rs_s[p0]);

    // ---- Stage 3a: per-(channel, slot) weighted 4-pixel sums into ps ----
#pragma unroll
    for (int k = 0; k < 16; ++k) {
        int c = wid * 16 + k;
        float wsum = rs4.x * (v[k].x - mu4.x) + rs4.y * (v[k].y - mu4.y)
                   + rs4.z * (v[k].z - mu4.z) + rs4.w * (v[k].w - mu4.w);
        ps[c * PS_PITCH + slot] = wsum;
    }
    __syncthreads();

    // ---- Stage 3b: pm (1024 threads = 4 patches x 256 channels) ----
    {
        const int pt = t >> 8;
        const int c  = t & 255;
        const float* row = &ps[c * PS_PITCH + pt * 16];
        float s = 0.f;
#pragma unroll
        for (int j = 0; j < 16; ++j) s += row[j];
        pm_s[pt * C_DIM + c] = gs[c] * s * (1.0f / 64.0f) + bs[c];
    }
    __syncthreads();

    // ---- Stage 4a: h = silu(w1 @ pm) for 4 patches; w1 [32][256] row-major ----
    {
        const int pat4 = t >> 8;       // patch 0..3
        const int r    = (t >> 3) & 31;
        const int k8   = t & 7;        // 8-way split of the dot
        const float4* wrow = reinterpret_cast<const float4*>(w1 + r * C_DIM + k8 * 32);
        const float* pmk = &pm_s[pat4 * C_DIM + k8 * 32];
        float s = 0.f;
#pragma unroll
        for (int j = 0; j < 8; ++j) {
            float4 wv = wrow[j];
            float4 pv = *reinterpret_cast<const float4*>(pmk + j * 4);
            s += wv.x * pv.x + wv.y * pv.y + wv.z * pv.z + wv.w * pv.w;
        }
        s += __shfl_down(s, 4, 8);
        s += __shfl_down(s, 2, 8);
        s += __shfl_down(s, 1, 8);
        if (k8 == 0) {
            float sig = 1.0f / (1.0f + __expf(-s));
            h_s[pat4 * R_DIM + r] = s * sig;
        }
    }
    __syncthreads();

    // ---- Stage 4b: gate = sigmoid(w2 @ h); fold gamma/beta; w2 [256][32] ----
    {
        const int pat4 = t >> 8;
        const int c4   = t & 255;
        const float4* wrow = reinterpret_cast<const float4*>(w2 + c4 * R_DIM);
        const float* hk = &h_s[pat4 * R_DIM];
        float s = 0.f;
#pragma unroll
        for (int j = 0; j < 8; ++j) {
            float4 wv = wrow[j];
            s += wv.x * hk[j * 4 + 0] + wv.y * hk[j * 4 + 1]
               + wv.z * hk[j * 4 + 2] + wv.w * hk[j * 4 + 3];
        }
        float gate = 1.0f / (1.0f + __expf(-s));
        AB_s[pat4 * C_DIM + c4] = make_float2(gs[c4] * gate, bs[c4] * gate);
    }
    __syncthreads();

    // ---- Stage 5: out = A*rs*(x-mu) + B from registers; dense nt stores ----
    {
        float* ob = out + rowoff + (unsigned)wid * 16u * CH_STRIDE;
#pragma unroll
        for (int k = 0; k < 16; ++k) {
            int c = wid * 16 + k;
            float2 ab = AB_s[pat * C_DIM + c];
            nfloat4 o;
            o.x = ab.x * rs4.x * (v[k].x - mu4.x) + ab.y;
            o.y = ab.x * rs4.y * (v[k].y - mu4.y) + ab.y;
            o.z = ab.x * rs4.z * (v[k].z - mu4.z) + ab.y;
            o.w = ab.x * rs4.w * (v[k].w - mu4.w) + ab.y;
            __builtin_nontemporal_store(o,
                reinterpret_cast<nfloat4*>(ob + (unsigned)k * CH_STRIDE));
        }
    }
}

extern "C" void kernel_launch(void* const* d_in, const int* in_sizes, int n_in,
                              void* d_out, int out_size, void* d_ws, size_t ws_size,
                              hipStream_t stream) {
    const float* x     = (const float*)d_in[0];
    const float* gamma = (const float*)d_in[1];
    const float* beta  = (const float*)d_in[2];
    const float* w1    = (const float*)d_in[3];
    const float* w2    = (const float*)d_in[4];
    float* out = (float*)d_out;

    const int B = in_sizes[0] / (C_DIM * HWDIM * HWDIM);   // 8
    const int nwg = B * 256;                               // 2048 four-patch groups

    lpa_fused_kernel<<<nwg, 1024, 0, stream>>>(x, gamma, beta, w1, w2, out);
}